// Round 4
// baseline (6672.814 us; speedup 1.0000x reference)
//
#include <hip/hip_runtime.h>

// ObjectMsgEncoder on MI355X. INPUTS/OUTPUT ARE FLOAT32 (per reference dtypes);
// comparison is done in bf16 space by the harness (2%-of-max threshold).
// R2/R3 NaN root cause: inputs were misread as bf16 -> f32 low halves decoded as
// garbage bf16 incl. NaN patterns. This round: f32 I/O, bf16 only internally.
//
// K0 cvt  : f32 -> bf16 weight conversion into ws (Wih,Whh,Wgr,Wbc,Wesa).
// K1 prep : olf0 = emb*mask (f32 -> bf16)
// K2 lstm : 2 LSTM passes (olf3 dead in reference), 16 blocks x 16 scenes,
//           K=512 ([x|h]) MFMA per step, gate-aligned n-tiles -> gate math in regs.
// K3 aterm: A_i/A_j = olf_l @ Wgr_{i,j}^T, one GEMM [21504,256]@[256,512] -> f32
// K4 mega : block = (scene b, j-tile of 4) -> 112 pairs (all 28 i's).
//           rlf0 -> 3x(Wgr_r GEMM + A-terms + Wbc GEMM + bezier tanh) -> Wesa GEMM
//           -> gscore (post-esa) -> BOTH softmaxes over i in-LDS (log-sum-exp)
//           -> partial out (sum over the block's 4 j's) as bf16.
// K5 out  : sum 7 j-tile partials, mask rows i >= count, write f32.
// ws: olf bf16 11.0MB + At f32 44.0MB + part bf16 25.7MB + wcv bf16 1.7MB = 82.4MB.

typedef __attribute__((ext_vector_type(8))) short short8;
typedef __attribute__((ext_vector_type(4))) float f32x4;

__device__ __forceinline__ float b2f(unsigned short u){
  union { unsigned int i; float f; } v; v.i = ((unsigned int)u) << 16; return v.f;
}
__device__ __forceinline__ unsigned short f2b(float f){
  union { float f; unsigned int i; } v; v.f = f;
  unsigned int i = v.i;
  unsigned int r = (i + 0x7FFFu + ((i >> 16) & 1u)) >> 16;
  return (unsigned short)r;
}
__device__ __forceinline__ float sigm(float x){ return 1.f/(1.f+__expf(-x)); }
__device__ __forceinline__ float tanh_f(float x){ float e = __expf(2.f*x); return 1.f - 2.f/(e+1.f); }

#define MFMA16(a,b,c) __builtin_amdgcn_mfma_f32_16x16x32_bf16((a),(b),(c),0,0,0)

// ---------------- K0: f32 -> bf16 weight conversion ----------------
__global__ __launch_bounds__(256) void k_cvt(const float* __restrict__ src,
                                             unsigned short* __restrict__ dst, int n){
  int i = blockIdx.x*256 + threadIdx.x;
  if (i < n) dst[i] = f2b(src[i]);
}

// ---------------- K1: olf0 = emb * mask (f32 -> bf16) ----------------
__global__ __launch_bounds__(256) void k_prep(const float* __restrict__ emb,
                                              const int* __restrict__ counts,
                                              unsigned short* __restrict__ olf){
  int bs = blockIdx.x;            // b*28+s
  int b = bs / 28; int s = bs - b*28;
  int e = threadIdx.x;
  olf[(size_t)bs*256 + e] = (s < counts[b]) ? f2b(emb[(size_t)bs*256 + e]) : (unsigned short)0;
}

// ---------------- K2: LSTM, 2 passes, bf16 olf, bf16 weights (cv) ----------------
__global__ __launch_bounds__(256) void k_lstm(unsigned short* __restrict__ olf,
                                              const int* __restrict__ counts,
                                              const unsigned short* __restrict__ Wih,
                                              const unsigned short* __restrict__ Whh,
                                              const float* __restrict__ bih,
                                              const float* __restrict__ bhh){
  __shared__ unsigned short Ab[16*520];   // [scene][k] 0..255 = x, 256..511 = h; stride 520
  const int tid = threadIdx.x;
  const int wid = tid >> 6, lane = tid & 63, col = lane & 15, quad = lane >> 4;
  const int sc0 = blockIdx.x * 16;

  float bz[4][4];
  #pragma unroll
  for (int g=0; g<4; ++g){
    #pragma unroll
    for (int tt=0; tt<4; ++tt){
      int u = wid*64 + tt*16 + col;
      bz[g][tt] = bih[g*256+u] + bhh[g*256+u];
    }
  }
  int cnt4[4];
  #pragma unroll
  for (int r=0; r<4; ++r) cnt4[r] = counts[sc0 + quad*4 + r];

  for (int l=0; l<2; ++l){
    const unsigned short* xin = olf + (size_t)l*7168*256;
    unsigned short* xout = olf + (size_t)(l+1)*7168*256;
    float cst[4][4];
    #pragma unroll
    for (int tt=0; tt<4; ++tt){
      #pragma unroll
      for (int r=0; r<4; ++r) cst[tt][r] = 0.f;
    }
    #pragma unroll
    for (int tt=0; tt<4; ++tt){
      #pragma unroll
      for (int r=0; r<4; ++r){
        int s = quad*4 + r;
        int u = wid*64 + tt*16 + col;
        Ab[s*520 + 256 + u] = 0;
        Ab[s*520 + u] = xin[(size_t)(sc0+s)*28*256 + u];
      }
    }
    __syncthreads();
    for (int t=0; t<28; ++t){
      f32x4 acc[4][4];
      #pragma unroll
      for (int g=0; g<4; ++g){
        #pragma unroll
        for (int tt=0; tt<4; ++tt) acc[g][tt] = (f32x4){0.f,0.f,0.f,0.f};
      }
      #pragma unroll
      for (int kt=0; kt<16; ++kt){
        short8 a = *(const short8*)&Ab[col*520 + kt*32 + quad*8];
        const unsigned short* wb = (kt < 8) ? (Wih + kt*32 + quad*8)
                                            : (Whh + (kt-8)*32 + quad*8);
        #pragma unroll
        for (int g=0; g<4; ++g){
          #pragma unroll
          for (int tt=0; tt<4; ++tt){
            int n = g*256 + wid*64 + tt*16 + col;
            short8 bf = *(const short8*)&wb[n*256];
            acc[g][tt] = MFMA16(a, bf, acc[g][tt]);
          }
        }
      }
      __syncthreads();   // all GEMM reads of Ab done before rewrite
      #pragma unroll
      for (int tt=0; tt<4; ++tt){
        #pragma unroll
        for (int r=0; r<4; ++r){
          int s = quad*4 + r;
          int u = wid*64 + tt*16 + col;
          float zi = acc[0][tt][r] + bz[0][tt];
          float zf = acc[1][tt][r] + bz[1][tt];
          float zg = acc[2][tt][r] + bz[2][tt];
          float zo = acc[3][tt][r] + bz[3][tt];
          float cc = sigm(zf)*cst[tt][r] + sigm(zi)*tanh_f(zg);
          cst[tt][r] = cc;
          float hh = sigm(zo)*tanh_f(cc);
          unsigned short hb = f2b(hh);
          Ab[s*520 + 256 + u] = hb;                       // raw h feeds recurrence
          xout[((size_t)(sc0+s)*28 + t)*256 + u] = (t < cnt4[r]) ? hb : (unsigned short)0;
          if (t+1 < 28)
            Ab[s*520 + u] = xin[((size_t)(sc0+s)*28 + t + 1)*256 + u];
        }
      }
      __syncthreads();
    }
  }
}

// ---------------- K3: A-terms, [21504,256]@[256,512] -> f32 ----------------
__global__ __launch_bounds__(256) void k_aterm(const unsigned short* __restrict__ olf,
                                               const unsigned short* __restrict__ Wgr,
                                               float* __restrict__ Aout){
  const int tid = threadIdx.x;
  const int wid = tid >> 6, lane = tid & 63, col = lane & 15, quad = lane >> 4;
  const int m0 = blockIdx.x*64 + wid*16;
  short8 af[8];
  #pragma unroll
  for (int kt=0; kt<8; ++kt)
    af[kt] = *(const short8*)&olf[(size_t)(m0 + col)*256 + kt*32 + quad*8];
  #pragma unroll 4
  for (int nt=0; nt<32; ++nt){
    int n = nt*16 + col;   // n<256: A_i (Wgr cols 0..255); else A_j (cols 256..511)
    const unsigned short* wb = (nt < 16) ? (Wgr + n*768) : (Wgr + (n-256)*768 + 256);
    f32x4 acc = (f32x4){0.f,0.f,0.f,0.f};
    #pragma unroll
    for (int kt=0; kt<8; ++kt){
      short8 bf = *(const short8*)&wb[kt*32 + quad*8];
      acc = MFMA16(af[kt], bf, acc);
    }
    #pragma unroll
    for (int r=0; r<4; ++r)
      Aout[(size_t)(m0 + quad*4 + r)*512 + nt*16 + col] = acc[r];
  }
}

// ---------------- K4: fused per-(scene, j-tile) pipeline ----------------
// Static LDS: 112*264*2 + 112*4 + 1024*4 + 4*4 = 63,696 B
__global__ __launch_bounds__(448) void k_mega(
    const float* __restrict__ centers, const int* __restrict__ counts,
    const float* __restrict__ Wr, const float* __restrict__ br,
    const unsigned short* __restrict__ Wgr, const float* __restrict__ bgr,
    const unsigned short* __restrict__ Wbc, const float* __restrict__ bbc,
    const float* __restrict__ alpha,
    const unsigned short* __restrict__ Wesa, const float* __restrict__ besa,
    const float* __restrict__ Wmu, const float* __restrict__ bmu,
    const float* __restrict__ Aterm, unsigned short* __restrict__ part){
  __shared__ unsigned short Xb[112*264];   // pair p = i*4+jc, 256 cols, stride 264
  __shared__ float gsb[112];
  __shared__ float lseB[1024];             // [jc*256+o]: max + ln(sum exp) over i
  __shared__ float lseG[4];                // per jc
  const int tid = threadIdx.x;
  const int wid = tid >> 6, lane = tid & 63, col = lane & 15, quad = lane >> 4;
  const int b = blockIdx.x / 7, jt = blockIdx.x - b*7;
  const int cb = counts[b];

  float av = alpha[0];
  float tv = sigm(av);
  float c1 = (1.f-tv)*(1.f-tv) + tv*tv;
  float c2 = 2.f*tv*(1.f-tv);

  int pis[4], pjs[4]; float pv[4];
  #pragma unroll
  for (int r=0; r<4; ++r){
    int p = wid*16 + quad*4 + r;        // local pair = C-row
    pis[r] = p >> 2;
    pjs[r] = jt*4 + (p & 3);
    pv[r] = (pis[r] < cb && pjs[r] < cb) ? 1.f : 0.f;
  }
  // S0: rlf0 = (mask_i*c_i - mask_j*c_j) @ Wr^T + br
  {
    int m = tid >> 2, sub = tid & 3;
    int i = m >> 2, j = jt*4 + (m & 3);
    float mi = (i < cb) ? 1.f : 0.f;
    float mj = (j < cb) ? 1.f : 0.f;
    const float* ci = centers + (b*28 + i)*3;
    const float* cj = centers + (b*28 + j)*3;
    float dx = mi*ci[0] - mj*cj[0];
    float dy = mi*ci[1] - mj*cj[1];
    float dz = mi*ci[2] - mj*cj[2];
    for (int e = sub*64; e < sub*64 + 64; ++e){
      float v = dx*Wr[e*3] + dy*Wr[e*3+1] + dz*Wr[e*3+2] + br[e];
      Xb[m*264 + e] = f2b(v);
    }
  }
  __syncthreads();

  const int arow = wid*16 + col;
  f32x4 Y[16], CP[16];
  #pragma unroll 1
  for (int l=0; l<3; ++l){
    // GEMM1: Y = rlf @ Wgr_r^T
    #pragma unroll
    for (int nt=0; nt<16; ++nt) Y[nt] = (f32x4){0.f,0.f,0.f,0.f};
    #pragma unroll
    for (int kt=0; kt<8; ++kt){
      short8 a = *(const short8*)&Xb[arow*264 + kt*32 + quad*8];
      #pragma unroll
      for (int nt=0; nt<16; ++nt){
        int n = nt*16 + col;
        short8 bf = *(const short8*)&Wgr[n*768 + 512 + kt*32 + quad*8];
        Y[nt] = MFMA16(a, bf, Y[nt]);
      }
    }
    __syncthreads();
    // S2: rlf_lin = Y + A_i + A_j + bgr ; stash bf16 copy for GEMM2
    size_t aib[4], ajb[4];
    #pragma unroll
    for (int r=0; r<4; ++r){
      aib[r] = ((size_t)l*7168 + b*28 + pis[r])*512;
      ajb[r] = ((size_t)l*7168 + b*28 + pjs[r])*512 + 256;
    }
    #pragma unroll
    for (int nt=0; nt<16; ++nt){
      int n = nt*16 + col;
      float bg = bgr[n];
      #pragma unroll
      for (int r=0; r<4; ++r){
        float v = Y[nt][r] + bg + Aterm[aib[r] + n] + Aterm[ajb[r] + n];
        Y[nt][r] = v;
        Xb[(wid*16 + quad*4 + r)*264 + n] = f2b(v);
      }
    }
    __syncthreads();
    // GEMM2: CP = rlf_lin @ Wbc^T
    #pragma unroll
    for (int nt=0; nt<16; ++nt) CP[nt] = (f32x4){0.f,0.f,0.f,0.f};
    #pragma unroll
    for (int kt=0; kt<8; ++kt){
      short8 a = *(const short8*)&Xb[arow*264 + kt*32 + quad*8];
      #pragma unroll
      for (int nt=0; nt<16; ++nt){
        int n = nt*16 + col;
        short8 bf = *(const short8*)&Wbc[n*256 + kt*32 + quad*8];
        CP[nt] = MFMA16(a, bf, CP[nt]);
      }
    }
    __syncthreads();
    // S4: rlf = tanh(c1*rlf_lin + c2*(CP+bbc)) * rel_mask
    #pragma unroll
    for (int nt=0; nt<16; ++nt){
      int n = nt*16 + col;
      float bb = bbc[n];
      #pragma unroll
      for (int r=0; r<4; ++r){
        float bez = c1*Y[nt][r] + c2*(CP[nt][r] + bb);
        Xb[(wid*16 + quad*4 + r)*264 + n] = f2b(tanh_f(bez) * pv[r]);
      }
    }
    __syncthreads();
  }
  // S5: resa = rlf @ Wesa^T + besa (regs) -> Xb bf16 + gscore from post-esa values
  #pragma unroll
  for (int nt=0; nt<16; ++nt) Y[nt] = (f32x4){0.f,0.f,0.f,0.f};
  #pragma unroll
  for (int kt=0; kt<8; ++kt){
    short8 a = *(const short8*)&Xb[arow*264 + kt*32 + quad*8];
    #pragma unroll
    for (int nt=0; nt<16; ++nt){
      int n = nt*16 + col;
      short8 bf = *(const short8*)&Wesa[n*256 + kt*32 + quad*8];
      Y[nt] = MFMA16(a, bf, Y[nt]);
    }
  }
  __syncthreads();   // all reads of rlf done before overwrite with resa
  float s4[4] = {0.f,0.f,0.f,0.f};
  #pragma unroll
  for (int nt=0; nt<16; ++nt){
    int n = nt*16 + col;
    float be = besa[n];
    float wmn = (Wmu[n] + Wmu[256+n] + Wmu[512+n]) * (1.f/3.f);
    #pragma unroll
    for (int r=0; r<4; ++r){
      float v = Y[nt][r] + be;
      Xb[(wid*16 + quad*4 + r)*264 + n] = f2b(v);
      s4[r] += v * wmn;
    }
  }
  #pragma unroll
  for (int r=0; r<4; ++r){
    s4[r] += __shfl_xor(s4[r], 1, 64);
    s4[r] += __shfl_xor(s4[r], 2, 64);
    s4[r] += __shfl_xor(s4[r], 4, 64);
    s4[r] += __shfl_xor(s4[r], 8, 64);
  }
  if (col == 0){
    float bm = (bmu[0] + bmu[1] + bmu[2]) * (1.f/3.f);
    #pragma unroll
    for (int r=0; r<4; ++r) gsb[wid*16 + quad*4 + r] = s4[r] + bm;
  }
  __syncthreads();
  // softmax stats over i (28 rows) per (jc,o) and per jc: lse = max + ln(sum exp)
  for (int it = tid; it < 1024; it += 448){
    int jc = it >> 8, o = it & 255;
    float mx = -1e30f;
    for (int i=0;i<28;++i) mx = fmaxf(mx, b2f(Xb[(i*4+jc)*264 + o]));
    float se = 0.f;
    for (int i=0;i<28;++i) se += __expf(b2f(Xb[(i*4+jc)*264 + o]) - mx);
    lseB[it] = mx + __logf(se);
  }
  if (tid < 4){
    int jc = tid;
    float mx = -1e30f;
    for (int i=0;i<28;++i) mx = fmaxf(mx, gsb[i*4+jc]);
    float se = 0.f;
    for (int i=0;i<28;++i) se += __expf(gsb[i*4+jc] - mx);
    lseG[jc] = mx + __logf(se);
  }
  __syncthreads();
  // partial output: sum over the block's 4 j's
  for (int it = tid; it < 7168; it += 448){
    int i = it >> 8, o = it & 255;
    float acc = 0.f;
    #pragma unroll
    for (int jc=0; jc<4; ++jc){
      int p = i*4 + jc;
      float v = b2f(Xb[p*264 + o]);
      float a = 0.5f*__expf(v - lseB[jc*256+o])
              + 0.5f*__expf(gsb[p] - lseG[jc]);
      acc += a * v;
    }
    part[((size_t)blockIdx.x*28 + i)*256 + o] = f2b(acc);
  }
}

// ---------------- K5: reduce 7 j-tiles, mask, write f32 ----------------
__global__ __launch_bounds__(256) void k_out(const unsigned short* __restrict__ part,
                                             const int* __restrict__ counts,
                                             float* __restrict__ out){
  int b = blockIdx.x / 28, i = blockIdx.x - b*28, o = threadIdx.x;
  float acc = 0.f;
  #pragma unroll
  for (int jt=0; jt<7; ++jt)
    acc += b2f(part[(((size_t)(b*7 + jt))*28 + i)*256 + o]);
  if (i >= counts[b]) acc = 0.f;
  out[(size_t)blockIdx.x*256 + o] = acc;
}

extern "C" void kernel_launch(void* const* d_in, const int* in_sizes, int n_in,
                              void* d_out, int out_size, void* d_ws, size_t ws_size,
                              hipStream_t stream){
  const float* centers = (const float*)d_in[0];
  const float* emb     = (const float*)d_in[1];
  const int*   counts  = (const int*)d_in[2];
  const float* Wr      = (const float*)d_in[3];
  const float* br      = (const float*)d_in[4];
  const float* Wih     = (const float*)d_in[5];
  const float* Whh     = (const float*)d_in[6];
  const float* bih     = (const float*)d_in[7];
  const float* bhh     = (const float*)d_in[8];
  const float* Wgr     = (const float*)d_in[9];
  const float* bgr     = (const float*)d_in[10];
  const float* Wbc     = (const float*)d_in[11];
  const float* bbc     = (const float*)d_in[12];
  const float* alpha   = (const float*)d_in[13];
  const float* Wesa    = (const float*)d_in[14];
  const float* besa    = (const float*)d_in[15];
  const float* Wmu     = (const float*)d_in[16];
  const float* bmu     = (const float*)d_in[17];
  // d_in[18], d_in[19] (Wlv, blv) are dead at eval time.

  // ws layout (82,444,288 bytes total):
  unsigned short* olf  = (unsigned short*)d_ws;                        // 3*7168*256 bf16 = 11,010,048 B
  float*          At   = (float*)((char*)d_ws + 11010048);             // 3*7168*512 f32  = 44,040,192 B
  unsigned short* part = (unsigned short*)((char*)d_ws + 55050240);    // 1792*28*256 bf16 = 25,690,112 B
  unsigned short* wcv  = (unsigned short*)((char*)d_ws + 80740352);    // 851,968 bf16 = 1,703,936 B
  unsigned short* cWih  = wcv;            // 262144
  unsigned short* cWhh  = wcv + 262144;   // 262144
  unsigned short* cWgr  = wcv + 524288;   // 196608
  unsigned short* cWbc  = wcv + 720896;   // 65536
  unsigned short* cWesa = wcv + 786432;   // 65536
  float* outp = (float*)d_out;

  hipLaunchKernelGGL(k_cvt, dim3(1024), dim3(256), 0, stream, Wih,  cWih,  262144);
  hipLaunchKernelGGL(k_cvt, dim3(1024), dim3(256), 0, stream, Whh,  cWhh,  262144);
  hipLaunchKernelGGL(k_cvt, dim3(768),  dim3(256), 0, stream, Wgr,  cWgr,  196608);
  hipLaunchKernelGGL(k_cvt, dim3(256),  dim3(256), 0, stream, Wbc,  cWbc,  65536);
  hipLaunchKernelGGL(k_cvt, dim3(256),  dim3(256), 0, stream, Wesa, cWesa, 65536);

  hipLaunchKernelGGL(k_prep, dim3(7168), dim3(256), 0, stream, emb, counts, olf);
  hipLaunchKernelGGL(k_lstm, dim3(16),   dim3(256), 0, stream, olf, counts, cWih, cWhh, bih, bhh);
  hipLaunchKernelGGL(k_aterm,dim3(336),  dim3(256), 0, stream, olf, cWgr, At);
  hipLaunchKernelGGL(k_mega, dim3(1792), dim3(448), 0, stream,
                     centers, counts, Wr, br, cWgr, bgr, cWbc, bbc, alpha,
                     cWesa, besa, Wmu, bmu, At, part);
  hipLaunchKernelGGL(k_out,  dim3(7168), dim3(256), 0, stream, part, counts, outp);
}

// Round 5
// 5537.827 us; speedup vs baseline: 1.2050x; 1.2050x over previous
//
#include <hip/hip_runtime.h>

// ObjectMsgEncoder on MI355X. f32 I/O, bf16 MFMA internally (f32 accumulate).
// R4 -> R5 changes:
//  * k_mega: CP[16] accumulator array eliminated (was 128 acc VGPRs -> wholesale
//    scratch spill: 3.85 GB WRITE_SIZE). rlf_lin lives in Xb (bf16); GEMM2 reuses
//    Y's registers; bezier re-reads rlf_lin from Xb.
//  * LSTM: x@Wih^T hoisted out of the recurrence (k_xgemm, parallel GEMM, bf16 zx
//    aliasing At's ws space). k_rec does h@Whh^T only (K=256), 512 thr / 8 waves
//    for latency hiding, per step streams 512 KB Whh from L2.
//  * At stored bf16 (halves A-term traffic).
// ws: olf 11.0MB + At 22.0MB (zx 14.7MB aliases it) + part 25.7MB + wcv 1.7MB = 60.4MB.

typedef __attribute__((ext_vector_type(8))) short short8;
typedef __attribute__((ext_vector_type(4))) float f32x4;

__device__ __forceinline__ float b2f(unsigned short u){
  union { unsigned int i; float f; } v; v.i = ((unsigned int)u) << 16; return v.f;
}
__device__ __forceinline__ unsigned short f2b(float f){
  union { float f; unsigned int i; } v; v.f = f;
  unsigned int i = v.i;
  unsigned int r = (i + 0x7FFFu + ((i >> 16) & 1u)) >> 16;
  return (unsigned short)r;
}
__device__ __forceinline__ float sigm(float x){ return 1.f/(1.f+__expf(-x)); }
__device__ __forceinline__ float tanh_f(float x){ float e = __expf(2.f*x); return 1.f - 2.f/(e+1.f); }

#define MFMA16(a,b,c) __builtin_amdgcn_mfma_f32_16x16x32_bf16((a),(b),(c),0,0,0)

// ---------------- K0: f32 -> bf16 weight conversion ----------------
__global__ __launch_bounds__(256) void k_cvt(const float* __restrict__ src,
                                             unsigned short* __restrict__ dst, int n){
  int i = blockIdx.x*256 + threadIdx.x;
  if (i < n) dst[i] = f2b(src[i]);
}

// ---------------- K1: olf0 = emb * mask (f32 -> bf16) ----------------
__global__ __launch_bounds__(256) void k_prep(const float* __restrict__ emb,
                                              const int* __restrict__ counts,
                                              unsigned short* __restrict__ olf){
  int bs = blockIdx.x;            // b*28+s
  int b = bs / 28; int s = bs - b*28;
  int e = threadIdx.x;
  olf[(size_t)bs*256 + e] = (s < counts[b]) ? f2b(emb[(size_t)bs*256 + e]) : (unsigned short)0;
}

// ---------------- K2a: zx = olf_l @ Wih^T  [7168,256]@[256,1024] -> bf16 ----------------
__global__ __launch_bounds__(256) void k_xgemm(const unsigned short* __restrict__ olf,
                                               const unsigned short* __restrict__ Wih,
                                               unsigned short* __restrict__ zx){
  const int tid = threadIdx.x;
  const int wid = tid >> 6, lane = tid & 63, col = lane & 15, quad = lane >> 4;
  const int m0 = blockIdx.x*64 + wid*16;
  short8 af[8];
  #pragma unroll
  for (int kt=0; kt<8; ++kt)
    af[kt] = *(const short8*)&olf[(size_t)(m0 + col)*256 + kt*32 + quad*8];
  #pragma unroll 4
  for (int nt=0; nt<64; ++nt){
    int n = nt*16 + col;
    f32x4 acc = (f32x4){0.f,0.f,0.f,0.f};
    #pragma unroll
    for (int kt=0; kt<8; ++kt){
      short8 bf = *(const short8*)&Wih[(size_t)n*256 + kt*32 + quad*8];
      acc = MFMA16(af[kt], bf, acc);
    }
    #pragma unroll
    for (int r=0; r<4; ++r)
      zx[(size_t)(m0 + quad*4 + r)*1024 + n] = f2b(acc[r]);
  }
}

// ---------------- K2b: LSTM recurrence, one layer: h@Whh^T + zx -> gates ----------------
// 16 blocks x 512 thr (8 waves). Wave wid owns, per gate g, units wid*32+tt*16+col (tt<2).
__global__ __launch_bounds__(512) void k_rec(const unsigned short* __restrict__ zx,
                                             const unsigned short* __restrict__ Whh,
                                             const float* __restrict__ bih,
                                             const float* __restrict__ bhh,
                                             const int* __restrict__ counts,
                                             unsigned short* __restrict__ olf_out){
  __shared__ unsigned short Ab[16*264];   // [scene][unit 0..255], stride 264
  const int tid = threadIdx.x;
  const int wid = tid >> 6, lane = tid & 63, col = lane & 15, quad = lane >> 4;
  const int sc0 = blockIdx.x * 16;

  float bz[4][2];
  #pragma unroll
  for (int g=0; g<4; ++g){
    #pragma unroll
    for (int tt=0; tt<2; ++tt){
      int u = wid*32 + tt*16 + col;
      bz[g][tt] = bih[g*256+u] + bhh[g*256+u];
    }
  }
  int cnt4[4];
  #pragma unroll
  for (int r=0; r<4; ++r) cnt4[r] = counts[sc0 + quad*4 + r];

  float cst[2][4];
  #pragma unroll
  for (int tt=0; tt<2; ++tt){
    #pragma unroll
    for (int r=0; r<4; ++r) cst[tt][r] = 0.f;
  }
  for (int i=tid; i<16*264; i+=512) Ab[i] = 0;   // h0 = 0
  __syncthreads();

  for (int t=0; t<28; ++t){
    // zx loads issued early (independent of MFMA chain)
    float zxv[4][2][4];
    #pragma unroll
    for (int g=0; g<4; ++g){
      #pragma unroll
      for (int tt=0; tt<2; ++tt){
        #pragma unroll
        for (int r=0; r<4; ++r)
          zxv[g][tt][r] = b2f(zx[((size_t)(sc0 + quad*4 + r)*28 + t)*1024
                                 + g*256 + wid*32 + tt*16 + col]);
      }
    }
    f32x4 acc[4][2];
    #pragma unroll
    for (int g=0; g<4; ++g){
      #pragma unroll
      for (int tt=0; tt<2; ++tt) acc[g][tt] = (f32x4){0.f,0.f,0.f,0.f};
    }
    #pragma unroll
    for (int kt=0; kt<8; ++kt){
      short8 a = *(const short8*)&Ab[col*264 + kt*32 + quad*8];
      #pragma unroll
      for (int g=0; g<4; ++g){
        #pragma unroll
        for (int tt=0; tt<2; ++tt){
          int n = g*256 + wid*32 + tt*16 + col;
          short8 bf = *(const short8*)&Whh[(size_t)n*256 + kt*32 + quad*8];
          acc[g][tt] = MFMA16(a, bf, acc[g][tt]);
        }
      }
    }
    __syncthreads();   // all reads of Ab(t) done
    #pragma unroll
    for (int tt=0; tt<2; ++tt){
      #pragma unroll
      for (int r=0; r<4; ++r){
        int s = quad*4 + r;
        int u = wid*32 + tt*16 + col;
        float zi = acc[0][tt][r] + zxv[0][tt][r] + bz[0][tt];
        float zf = acc[1][tt][r] + zxv[1][tt][r] + bz[1][tt];
        float zg = acc[2][tt][r] + zxv[2][tt][r] + bz[2][tt];
        float zo = acc[3][tt][r] + zxv[3][tt][r] + bz[3][tt];
        float cc = sigm(zf)*cst[tt][r] + sigm(zi)*tanh_f(zg);
        cst[tt][r] = cc;
        float hh = sigm(zo)*tanh_f(cc);
        unsigned short hb = f2b(hh);
        Ab[s*264 + u] = hb;                                   // raw h feeds recurrence
        olf_out[((size_t)(sc0+s)*28 + t)*256 + u] = (t < cnt4[r]) ? hb : (unsigned short)0;
      }
    }
    __syncthreads();
  }
}

// ---------------- K3: A-terms, [21504,256]@[256,512] -> bf16 ----------------
__global__ __launch_bounds__(256) void k_aterm(const unsigned short* __restrict__ olf,
                                               const unsigned short* __restrict__ Wgr,
                                               unsigned short* __restrict__ Aout){
  const int tid = threadIdx.x;
  const int wid = tid >> 6, lane = tid & 63, col = lane & 15, quad = lane >> 4;
  const int m0 = blockIdx.x*64 + wid*16;
  short8 af[8];
  #pragma unroll
  for (int kt=0; kt<8; ++kt)
    af[kt] = *(const short8*)&olf[(size_t)(m0 + col)*256 + kt*32 + quad*8];
  #pragma unroll 4
  for (int nt=0; nt<32; ++nt){
    int n = nt*16 + col;   // n<256: A_i (Wgr cols 0..255); else A_j (cols 256..511)
    const unsigned short* wb = (nt < 16) ? (Wgr + n*768) : (Wgr + (n-256)*768 + 256);
    f32x4 acc = (f32x4){0.f,0.f,0.f,0.f};
    #pragma unroll
    for (int kt=0; kt<8; ++kt){
      short8 bf = *(const short8*)&wb[kt*32 + quad*8];
      acc = MFMA16(af[kt], bf, acc);
    }
    #pragma unroll
    for (int r=0; r<4; ++r)
      Aout[(size_t)(m0 + quad*4 + r)*512 + nt*16 + col] = f2b(acc[r]);
  }
}

// ---------------- K4: fused per-(scene, j-tile) pipeline ----------------
// Static LDS: 112*264*2 + 112*4 + 1024*4 + 4*4 = 63,696 B
__global__ __launch_bounds__(448) void k_mega(
    const float* __restrict__ centers, const int* __restrict__ counts,
    const float* __restrict__ Wr, const float* __restrict__ br,
    const unsigned short* __restrict__ Wgr, const float* __restrict__ bgr,
    const unsigned short* __restrict__ Wbc, const float* __restrict__ bbc,
    const float* __restrict__ alpha,
    const unsigned short* __restrict__ Wesa, const float* __restrict__ besa,
    const float* __restrict__ Wmu, const float* __restrict__ bmu,
    const unsigned short* __restrict__ Aterm, unsigned short* __restrict__ part){
  __shared__ unsigned short Xb[112*264];   // pair p = i*4+jc, 256 cols, stride 264
  __shared__ float gsb[112];
  __shared__ float lseB[1024];             // [jc*256+o]: max + ln(sum exp) over i
  __shared__ float lseG[4];                // per jc
  const int tid = threadIdx.x;
  const int wid = tid >> 6, lane = tid & 63, col = lane & 15, quad = lane >> 4;
  const int b = blockIdx.x / 7, jt = blockIdx.x - b*7;
  const int cb = counts[b];

  float av = alpha[0];
  float tv = sigm(av);
  float c1 = (1.f-tv)*(1.f-tv) + tv*tv;
  float c2 = 2.f*tv*(1.f-tv);

  int pis[4], pjs[4]; float pv[4];
  #pragma unroll
  for (int r=0; r<4; ++r){
    int p = wid*16 + quad*4 + r;        // local pair = C-row
    pis[r] = p >> 2;
    pjs[r] = jt*4 + (p & 3);
    pv[r] = (pis[r] < cb && pjs[r] < cb) ? 1.f : 0.f;
  }
  // S0: rlf0 = (mask_i*c_i - mask_j*c_j) @ Wr^T + br
  {
    int m = tid >> 2, sub = tid & 3;
    int i = m >> 2, j = jt*4 + (m & 3);
    float mi = (i < cb) ? 1.f : 0.f;
    float mj = (j < cb) ? 1.f : 0.f;
    const float* ci = centers + (b*28 + i)*3;
    const float* cj = centers + (b*28 + j)*3;
    float dx = mi*ci[0] - mj*cj[0];
    float dy = mi*ci[1] - mj*cj[1];
    float dz = mi*ci[2] - mj*cj[2];
    for (int e = sub*64; e < sub*64 + 64; ++e){
      float v = dx*Wr[e*3] + dy*Wr[e*3+1] + dz*Wr[e*3+2] + br[e];
      Xb[m*264 + e] = f2b(v);
    }
  }
  __syncthreads();

  const int arow = wid*16 + col;
  f32x4 Y[16];
  #pragma unroll 1
  for (int l=0; l<3; ++l){
    // GEMM1: Y = rlf @ Wgr_r^T
    #pragma unroll
    for (int nt=0; nt<16; ++nt) Y[nt] = (f32x4){0.f,0.f,0.f,0.f};
    #pragma unroll
    for (int kt=0; kt<8; ++kt){
      short8 a = *(const short8*)&Xb[arow*264 + kt*32 + quad*8];
      #pragma unroll
      for (int nt=0; nt<16; ++nt){
        int n = nt*16 + col;
        short8 bf = *(const short8*)&Wgr[n*768 + 512 + kt*32 + quad*8];
        Y[nt] = MFMA16(a, bf, Y[nt]);
      }
    }
    __syncthreads();
    // S2: rlf_lin = Y + A_i + A_j + bgr -> Xb (bf16). Y registers are then free.
    size_t aib[4], ajb[4];
    #pragma unroll
    for (int r=0; r<4; ++r){
      aib[r] = ((size_t)l*7168 + b*28 + pis[r])*512;
      ajb[r] = ((size_t)l*7168 + b*28 + pjs[r])*512 + 256;
    }
    #pragma unroll
    for (int nt=0; nt<16; ++nt){
      int n = nt*16 + col;
      float bg = bgr[n];
      #pragma unroll
      for (int r=0; r<4; ++r){
        float v = Y[nt][r] + bg + b2f(Aterm[aib[r] + n]) + b2f(Aterm[ajb[r] + n]);
        Xb[(wid*16 + quad*4 + r)*264 + n] = f2b(v);
      }
    }
    __syncthreads();
    // GEMM2: Y = rlf_lin @ Wbc^T (reuses Y's registers -> no spill)
    #pragma unroll
    for (int nt=0; nt<16; ++nt) Y[nt] = (f32x4){0.f,0.f,0.f,0.f};
    #pragma unroll
    for (int kt=0; kt<8; ++kt){
      short8 a = *(const short8*)&Xb[arow*264 + kt*32 + quad*8];
      #pragma unroll
      for (int nt=0; nt<16; ++nt){
        int n = nt*16 + col;
        short8 bf = *(const short8*)&Wbc[n*256 + kt*32 + quad*8];
        Y[nt] = MFMA16(a, bf, Y[nt]);
      }
    }
    __syncthreads();
    // S4: rlf = tanh(c1*rlf_lin + c2*(CP+bbc)) * rel_mask ; rlf_lin re-read from Xb
    #pragma unroll
    for (int nt=0; nt<16; ++nt){
      int n = nt*16 + col;
      float bb = bbc[n];
      #pragma unroll
      for (int r=0; r<4; ++r){
        int off = (wid*16 + quad*4 + r)*264 + n;
        float rl = b2f(Xb[off]);
        float bez = c1*rl + c2*(Y[nt][r] + bb);
        Xb[off] = f2b(tanh_f(bez) * pv[r]);
      }
    }
    __syncthreads();
  }
  // S5: resa = rlf @ Wesa^T + besa -> Xb bf16 + gscore from post-esa values
  #pragma unroll
  for (int nt=0; nt<16; ++nt) Y[nt] = (f32x4){0.f,0.f,0.f,0.f};
  #pragma unroll
  for (int kt=0; kt<8; ++kt){
    short8 a = *(const short8*)&Xb[arow*264 + kt*32 + quad*8];
    #pragma unroll
    for (int nt=0; nt<16; ++nt){
      int n = nt*16 + col;
      short8 bf = *(const short8*)&Wesa[n*256 + kt*32 + quad*8];
      Y[nt] = MFMA16(a, bf, Y[nt]);
    }
  }
  __syncthreads();   // all reads of rlf done before overwrite with resa
  float s4[4] = {0.f,0.f,0.f,0.f};
  #pragma unroll
  for (int nt=0; nt<16; ++nt){
    int n = nt*16 + col;
    float be = besa[n];
    float wmn = (Wmu[n] + Wmu[256+n] + Wmu[512+n]) * (1.f/3.f);
    #pragma unroll
    for (int r=0; r<4; ++r){
      float v = Y[nt][r] + be;
      Xb[(wid*16 + quad*4 + r)*264 + n] = f2b(v);
      s4[r] += v * wmn;
    }
  }
  #pragma unroll
  for (int r=0; r<4; ++r){
    s4[r] += __shfl_xor(s4[r], 1, 64);
    s4[r] += __shfl_xor(s4[r], 2, 64);
    s4[r] += __shfl_xor(s4[r], 4, 64);
    s4[r] += __shfl_xor(s4[r], 8, 64);
  }
  if (col == 0){
    float bm = (bmu[0] + bmu[1] + bmu[2]) * (1.f/3.f);
    #pragma unroll
    for (int r=0; r<4; ++r) gsb[wid*16 + quad*4 + r] = s4[r] + bm;
  }
  __syncthreads();
  // softmax stats over i (28 rows) per (jc,o) and per jc: lse = max + ln(sum exp)
  for (int it = tid; it < 1024; it += 448){
    int jc = it >> 8, o = it & 255;
    float mx = -1e30f;
    for (int i=0;i<28;++i) mx = fmaxf(mx, b2f(Xb[(i*4+jc)*264 + o]));
    float se = 0.f;
    for (int i=0;i<28;++i) se += __expf(b2f(Xb[(i*4+jc)*264 + o]) - mx);
    lseB[it] = mx + __logf(se);
  }
  if (tid < 4){
    int jc = tid;
    float mx = -1e30f;
    for (int i=0;i<28;++i) mx = fmaxf(mx, gsb[i*4+jc]);
    float se = 0.f;
    for (int i=0;i<28;++i) se += __expf(gsb[i*4+jc] - mx);
    lseG[jc] = mx + __logf(se);
  }
  __syncthreads();
  // partial output: sum over the block's 4 j's
  for (int it = tid; it < 7168; it += 448){
    int i = it >> 8, o = it & 255;
    float acc = 0.f;
    #pragma unroll
    for (int jc=0; jc<4; ++jc){
      int p = i*4 + jc;
      float v = b2f(Xb[p*264 + o]);
      float a = 0.5f*__expf(v - lseB[jc*256+o])
              + 0.5f*__expf(gsb[p] - lseG[jc]);
      acc += a * v;
    }
    part[((size_t)blockIdx.x*28 + i)*256 + o] = f2b(acc);
  }
}

// ---------------- K5: reduce 7 j-tiles, mask, write f32 ----------------
__global__ __launch_bounds__(256) void k_out(const unsigned short* __restrict__ part,
                                             const int* __restrict__ counts,
                                             float* __restrict__ out){
  int b = blockIdx.x / 28, i = blockIdx.x - b*28, o = threadIdx.x;
  float acc = 0.f;
  #pragma unroll
  for (int jt=0; jt<7; ++jt)
    acc += b2f(part[(((size_t)(b*7 + jt))*28 + i)*256 + o]);
  if (i >= counts[b]) acc = 0.f;
  out[(size_t)blockIdx.x*256 + o] = acc;
}

extern "C" void kernel_launch(void* const* d_in, const int* in_sizes, int n_in,
                              void* d_out, int out_size, void* d_ws, size_t ws_size,
                              hipStream_t stream){
  const float* centers = (const float*)d_in[0];
  const float* emb     = (const float*)d_in[1];
  const int*   counts  = (const int*)d_in[2];
  const float* Wr      = (const float*)d_in[3];
  const float* br      = (const float*)d_in[4];
  const float* Wih     = (const float*)d_in[5];
  const float* Whh     = (const float*)d_in[6];
  const float* bih     = (const float*)d_in[7];
  const float* bhh     = (const float*)d_in[8];
  const float* Wgr     = (const float*)d_in[9];
  const float* bgr     = (const float*)d_in[10];
  const float* Wbc     = (const float*)d_in[11];
  const float* bbc     = (const float*)d_in[12];
  const float* alpha   = (const float*)d_in[13];
  const float* Wesa    = (const float*)d_in[14];
  const float* besa    = (const float*)d_in[15];
  const float* Wmu     = (const float*)d_in[16];
  const float* bmu     = (const float*)d_in[17];
  // d_in[18], d_in[19] (Wlv, blv) are dead at eval time.

  // ws layout (60,424,192 bytes total):
  unsigned short* olf  = (unsigned short*)d_ws;                        // 3*7168*256 bf16 = 11,010,048 B
  unsigned short* At   = (unsigned short*)((char*)d_ws + 11010048);    // 3*7168*512 bf16 = 22,020,096 B
  unsigned short* zx   = At;                                           // 7168*1024 bf16 = 14,680,064 B (aliases At; used before k_aterm)
  unsigned short* part = (unsigned short*)((char*)d_ws + 33030144);    // 1792*28*256 bf16 = 25,690,112 B
  unsigned short* wcv  = (unsigned short*)((char*)d_ws + 58720256);    // 851,968 bf16 = 1,703,936 B
  unsigned short* cWih  = wcv;            // 262144
  unsigned short* cWhh  = wcv + 262144;   // 262144
  unsigned short* cWgr  = wcv + 524288;   // 196608
  unsigned short* cWbc  = wcv + 720896;   // 65536
  unsigned short* cWesa = wcv + 786432;   // 65536
  float* outp = (float*)d_out;

  hipLaunchKernelGGL(k_cvt, dim3(1024), dim3(256), 0, stream, Wih,  cWih,  262144);
  hipLaunchKernelGGL(k_cvt, dim3(1024), dim3(256), 0, stream, Whh,  cWhh,  262144);
  hipLaunchKernelGGL(k_cvt, dim3(768),  dim3(256), 0, stream, Wgr,  cWgr,  196608);
  hipLaunchKernelGGL(k_cvt, dim3(256),  dim3(256), 0, stream, Wbc,  cWbc,  65536);
  hipLaunchKernelGGL(k_cvt, dim3(256),  dim3(256), 0, stream, Wesa, cWesa, 65536);

  hipLaunchKernelGGL(k_prep, dim3(7168), dim3(256), 0, stream, emb, counts, olf);
  // LSTM pass 1: olf0 -> olf1
  hipLaunchKernelGGL(k_xgemm, dim3(112), dim3(256), 0, stream, olf, cWih, zx);
  hipLaunchKernelGGL(k_rec,   dim3(16),  dim3(512), 0, stream, zx, cWhh, bih, bhh, counts,
                     olf + (size_t)7168*256);
  // LSTM pass 2: olf1 -> olf2
  hipLaunchKernelGGL(k_xgemm, dim3(112), dim3(256), 0, stream, olf + (size_t)7168*256, cWih, zx);
  hipLaunchKernelGGL(k_rec,   dim3(16),  dim3(512), 0, stream, zx, cWhh, bih, bhh, counts,
                     olf + (size_t)2*7168*256);
  hipLaunchKernelGGL(k_aterm, dim3(336), dim3(256), 0, stream, olf, cWgr, At);
  hipLaunchKernelGGL(k_mega,  dim3(1792), dim3(448), 0, stream,
                     centers, counts, Wr, br, cWgr, bgr, cWbc, bbc, alpha,
                     cWesa, besa, Wmu, bmu, At, part);
  hipLaunchKernelGGL(k_out,   dim3(7168), dim3(256), 0, stream, part, counts, outp);
}